// Round 1
// baseline (7435.083 us; speedup 1.0000x reference)
//
#include <hip/hip_runtime.h>
#include <hip/hip_bf16.h>

#define HH 1024
#define BATCH 32
#define SSRC 256
#define SDEC 64
#define EDIM 512
#define VOC 32000

typedef __attribute__((ext_vector_type(8))) short bf16x8_t;
typedef __attribute__((ext_vector_type(4))) short s16x4_t;
typedef __attribute__((ext_vector_type(4))) float f32x4_t;

__device__ __forceinline__ float bf2f(unsigned short u) {
  union { float f; unsigned int i; } c; c.i = ((unsigned int)u) << 16; return c.f;
}
__device__ __forceinline__ unsigned short f2bf(float f) {
  union { float f; unsigned int i; } c; c.f = f;
  unsigned int r = c.i + 0x7fffu + ((c.i >> 16) & 1u);
  return (unsigned short)(r >> 16);
}
__device__ __forceinline__ f32x4_t mfma16(bf16x8_t a, bf16x8_t b, f32x4_t c) {
  return __builtin_amdgcn_mfma_f32_16x16x32_bf16(a, b, c, 0, 0, 0);
}

// ---------- transpose f32 (K,N) -> bf16 (N,K) ----------
__global__ void k_transpose_bf16(const float* __restrict__ in, unsigned short* __restrict__ out,
                                 int K, int N) {
  __shared__ float tile[32][33];
  int n0 = blockIdx.x * 32, k0 = blockIdx.y * 32;
  int tx = threadIdx.x, ty = threadIdx.y;
#pragma unroll
  for (int i = 0; i < 4; i++)
    tile[ty + i * 8][tx] = in[(size_t)(k0 + ty + i * 8) * N + (n0 + tx)];
  __syncthreads();
#pragma unroll
  for (int i = 0; i < 4; i++)
    out[(size_t)(n0 + ty + i * 8) * K + (k0 + tx)] = f2bf(tile[tx][ty + i * 8]);
}

// ---------- embedding gather -> bf16 ----------
__global__ void k_embed(const int* __restrict__ seq, const float* __restrict__ emb,
                        unsigned short* __restrict__ out) {
  int t = blockIdx.x;
  int row = seq[t];
  const float* s = emb + (size_t)row * EDIM;
  unsigned short* d = out + (size_t)t * EDIM;
  for (int e = threadIdx.x; e < EDIM; e += blockDim.x) d[e] = f2bf(s[e]);
}

// ---------- big GEMM: C[M,N] = A[M,K](bf16) * B^T[N,K](bf16) + bias ----------
template <int OUT_BF16>
__global__ __launch_bounds__(256) void k_gemm_bt(const unsigned short* __restrict__ A,
                                                 const unsigned short* __restrict__ B,
                                                 const float* __restrict__ bias,
                                                 void* __restrict__ Cv, int M, int N, int K) {
  __shared__ unsigned short As[128 * 32];
  __shared__ unsigned short Bs[128 * 32];
  const int tid = threadIdx.x;
  const int wave = tid >> 6, lane = tid & 63;
  const int row0 = blockIdx.y * 128, col0 = blockIdx.x * 128;
  const int wr = (wave >> 1) * 64, wc = (wave & 1) * 64;
  const int lrow = lane & 15, lk8 = (lane >> 4) * 8;
  f32x4_t acc[4][4] = {};
  const int c1 = wave, c2 = wave + 4;
  const int sr1 = c1 * 16 + (lane >> 2), sr2 = c2 * 16 + (lane >> 2);
  const int sk = (lane & 3) * 8;
  for (int kt = 0; kt < K; kt += 32) {
    __builtin_amdgcn_global_load_lds(
        (const __attribute__((address_space(1))) unsigned int*)(A + (size_t)(row0 + sr1) * K + kt + sk),
        (__attribute__((address_space(3))) unsigned int*)(As + c1 * 512), 16, 0, 0);
    __builtin_amdgcn_global_load_lds(
        (const __attribute__((address_space(1))) unsigned int*)(A + (size_t)(row0 + sr2) * K + kt + sk),
        (__attribute__((address_space(3))) unsigned int*)(As + c2 * 512), 16, 0, 0);
    __builtin_amdgcn_global_load_lds(
        (const __attribute__((address_space(1))) unsigned int*)(B + (size_t)(col0 + sr1) * K + kt + sk),
        (__attribute__((address_space(3))) unsigned int*)(Bs + c1 * 512), 16, 0, 0);
    __builtin_amdgcn_global_load_lds(
        (const __attribute__((address_space(1))) unsigned int*)(B + (size_t)(col0 + sr2) * K + kt + sk),
        (__attribute__((address_space(3))) unsigned int*)(Bs + c2 * 512), 16, 0, 0);
    __syncthreads();
    bf16x8_t af[4], bfr[4];
#pragma unroll
    for (int i = 0; i < 4; i++) {
      af[i] = *(const bf16x8_t*)(As + (wr + i * 16 + lrow) * 32 + lk8);
      bfr[i] = *(const bf16x8_t*)(Bs + (wc + i * 16 + lrow) * 32 + lk8);
    }
#pragma unroll
    for (int i = 0; i < 4; i++)
#pragma unroll
      for (int j = 0; j < 4; j++) acc[i][j] = mfma16(af[i], bfr[j], acc[i][j]);
    __syncthreads();
  }
#pragma unroll
  for (int j = 0; j < 4; j++) {
    int col = col0 + wc + j * 16 + lrow;
    float bv = bias ? bias[col] : 0.0f;
#pragma unroll
    for (int i = 0; i < 4; i++) {
#pragma unroll
      for (int r = 0; r < 4; r++) {
        int row = row0 + wr + i * 16 + (lane >> 4) * 4 + r;
        float v = acc[i][j][r] + bv;
        if (OUT_BF16)
          ((unsigned short*)Cv)[(size_t)row * N + col] = f2bf(v);
        else
          ((float*)Cv)[(size_t)row * N + col] = v;
      }
    }
  }
}

// ---------- small GEMM M=32: C[32,N](bf16) = A[32,K](bf16) * B^T[N,K](bf16) ----------
__global__ __launch_bounds__(64) void k_gemm_m32(const unsigned short* __restrict__ A,
                                                 const unsigned short* __restrict__ B,
                                                 unsigned short* __restrict__ C, int N, int K) {
  int lane = threadIdx.x;
  int n0 = blockIdx.x * 16;
  int lrow = lane & 15, lk8 = (lane >> 4) * 8;
  f32x4_t acc0 = {}, acc1 = {};
  for (int kt = 0; kt < K; kt += 32) {
    bf16x8_t b = *(const bf16x8_t*)(B + (size_t)(n0 + lrow) * K + kt + lk8);
    bf16x8_t x0 = *(const bf16x8_t*)(A + (size_t)lrow * K + kt + lk8);
    bf16x8_t x1 = *(const bf16x8_t*)(A + (size_t)(16 + lrow) * K + kt + lk8);
    acc0 = mfma16(x0, b, acc0);
    acc1 = mfma16(x1, b, acc1);
  }
#pragma unroll
  for (int r = 0; r < 4; r++) {
    int row = (lane >> 4) * 4 + r;
    C[(size_t)row * N + n0 + lrow] = f2bf(acc0[r]);
    C[(size_t)(row + 16) * N + n0 + lrow] = f2bf(acc1[r]);
  }
}

// ---------- encoder GRU step: gh = h@Wh, gates, h_new, enc_hiddens write ----------
__global__ __launch_bounds__(192) void k_enc_step(const unsigned short* __restrict__ h_bf,
                                                  const float* __restrict__ h_f32,
                                                  const unsigned short* __restrict__ gx_t,
                                                  const unsigned short* __restrict__ WhT,
                                                  float* __restrict__ ho_f32,
                                                  unsigned short* __restrict__ ho_bf,
                                                  unsigned short* __restrict__ ench_t) {
  __shared__ float gs[3][32][16];
  const int tid = threadIdx.x;
  const int wave = tid >> 6, lane = tid & 63;
  const int j0 = blockIdx.x * 16;
  const int lrow = lane & 15, lk8 = (lane >> 4) * 8;
  const int nb = wave * HH + j0;
  f32x4_t acc0 = {}, acc1 = {};
  for (int kt = 0; kt < HH; kt += 32) {
    bf16x8_t b = *(const bf16x8_t*)(WhT + (size_t)(nb + lrow) * HH + kt + lk8);
    bf16x8_t x0 = *(const bf16x8_t*)(h_bf + lrow * HH + kt + lk8);
    bf16x8_t x1 = *(const bf16x8_t*)(h_bf + (16 + lrow) * HH + kt + lk8);
    acc0 = mfma16(x0, b, acc0);
    acc1 = mfma16(x1, b, acc1);
  }
#pragma unroll
  for (int r = 0; r < 4; r++) {
    gs[wave][(lane >> 4) * 4 + r][lrow] = acc0[r];
    gs[wave][(lane >> 4) * 4 + r + 16][lrow] = acc1[r];
  }
  __syncthreads();
  for (int idx = tid; idx < 512; idx += 192) {
    int b = idx >> 4, jj = idx & 15, j = j0 + jj;
    size_t gxo = (size_t)b * (SSRC * 3 * HH);
    float xz = bf2f(gx_t[gxo + j]);
    float xr = bf2f(gx_t[gxo + HH + j]);
    float xh = bf2f(gx_t[gxo + 2 * HH + j]);
    float hz = gs[0][b][jj], hr = gs[1][b][jj], hh = gs[2][b][jj];
    float z = 1.0f / (1.0f + expf(-(xz + hz)));
    float r = 1.0f / (1.0f + expf(-(xr + hr)));
    float cand = tanhf(xh + r * hh);
    float hp = h_f32[b * HH + j];
    float hn = z * hp + (1.0f - z) * cand;
    ho_f32[b * HH + j] = hn;
    unsigned short hv = f2bf(hn);
    ho_bf[b * HH + j] = hv;
    ench_t[(size_t)b * (SSRC * HH) + j] = hv;
  }
}

// ---------- decoder GRU step: gxc = ctx@WxD2 (+xpart), gh = h@Wh, gates ----------
__global__ __launch_bounds__(384) void k_dec_step(const unsigned short* __restrict__ h_bf,
                                                  const float* __restrict__ h_f32,
                                                  const unsigned short* __restrict__ ctx_bf,
                                                  const unsigned short* __restrict__ xp_t,
                                                  const unsigned short* __restrict__ WxD2T,
                                                  const unsigned short* __restrict__ WhDT,
                                                  float* __restrict__ ho_f32,
                                                  unsigned short* __restrict__ ho_bf,
                                                  unsigned short* __restrict__ deco_t) {
  __shared__ float gs[6][32][16];
  const int tid = threadIdx.x;
  const int wave = tid >> 6, lane = tid & 63;
  const int j0 = blockIdx.x * 16;
  const int lrow = lane & 15, lk8 = (lane >> 4) * 8;
  const unsigned short* Ap = (wave < 3) ? ctx_bf : h_bf;
  const unsigned short* Bp = (wave < 3) ? WxD2T : WhDT;
  const int gchunk = (wave < 3) ? wave : wave - 3;
  const int nb = gchunk * HH + j0;
  f32x4_t acc0 = {}, acc1 = {};
  for (int kt = 0; kt < HH; kt += 32) {
    bf16x8_t b = *(const bf16x8_t*)(Bp + (size_t)(nb + lrow) * HH + kt + lk8);
    bf16x8_t x0 = *(const bf16x8_t*)(Ap + lrow * HH + kt + lk8);
    bf16x8_t x1 = *(const bf16x8_t*)(Ap + (16 + lrow) * HH + kt + lk8);
    acc0 = mfma16(x0, b, acc0);
    acc1 = mfma16(x1, b, acc1);
  }
#pragma unroll
  for (int r = 0; r < 4; r++) {
    gs[wave][(lane >> 4) * 4 + r][lrow] = acc0[r];
    gs[wave][(lane >> 4) * 4 + r + 16][lrow] = acc1[r];
  }
  __syncthreads();
  for (int idx = tid; idx < 512; idx += 384) {
    int b = idx >> 4, jj = idx & 15, j = j0 + jj;
    size_t xpo = (size_t)b * (SDEC * 3 * HH);
    float xz = gs[0][b][jj] + bf2f(xp_t[xpo + j]);
    float xr = gs[1][b][jj] + bf2f(xp_t[xpo + HH + j]);
    float xh = gs[2][b][jj] + bf2f(xp_t[xpo + 2 * HH + j]);
    float hz = gs[3][b][jj], hr = gs[4][b][jj], hh = gs[5][b][jj];
    float z = 1.0f / (1.0f + expf(-(xz + hz)));
    float r = 1.0f / (1.0f + expf(-(xr + hr)));
    float cand = tanhf(xh + r * hh);
    float hp = h_f32[b * HH + j];
    float hn = z * hp + (1.0f - z) * cand;
    ho_f32[b * HH + j] = hn;
    unsigned short hv = f2bf(hn);
    ho_bf[b * HH + j] = hv;
    deco_t[(size_t)b * (SDEC * HH) + j] = hv;
  }
}

// ---------- attention: scores -> softmax -> ctx, one block per batch ----------
__global__ __launch_bounds__(256) void k_attn(const unsigned short* __restrict__ ench,
                                              const unsigned short* __restrict__ svec,
                                              unsigned short* __restrict__ ctx) {
  __shared__ float red[256];
  __shared__ float wts[256];
  const int b = blockIdx.x, tid = threadIdx.x;
  const unsigned short* row = ench + ((size_t)b * SSRC + tid) * HH;
  const unsigned short* sv = svec + (size_t)b * HH;
  float acc = 0.0f;
  for (int k = 0; k < HH; k += 8) {
    bf16x8_t e = *(const bf16x8_t*)(row + k);
    bf16x8_t s = *(const bf16x8_t*)(sv + k);
#pragma unroll
    for (int j = 0; j < 8; j++) acc += bf2f((unsigned short)e[j]) * bf2f((unsigned short)s[j]);
  }
  red[tid] = acc;
  __syncthreads();
  for (int o = 128; o > 0; o >>= 1) {
    if (tid < o) red[tid] = fmaxf(red[tid], red[tid + o]);
    __syncthreads();
  }
  float mx = red[0];
  __syncthreads();
  float e = expf(acc - mx);
  red[tid] = e;
  __syncthreads();
  for (int o = 128; o > 0; o >>= 1) {
    if (tid < o) red[tid] += red[tid + o];
    __syncthreads();
  }
  float inv = 1.0f / red[0];
  wts[tid] = e * inv;
  __syncthreads();
  float a0 = 0, a1 = 0, a2 = 0, a3 = 0;
  const unsigned short* base = ench + (size_t)b * SSRC * HH + tid * 4;
  for (int s = 0; s < SSRC; s++) {
    float w = wts[s];
    s16x4_t v = *(const s16x4_t*)(base + (size_t)s * HH);
    a0 += w * bf2f((unsigned short)v[0]);
    a1 += w * bf2f((unsigned short)v[1]);
    a2 += w * bf2f((unsigned short)v[2]);
    a3 += w * bf2f((unsigned short)v[3]);
  }
  unsigned short* c = ctx + (size_t)b * HH + tid * 4;
  c[0] = f2bf(a0);
  c[1] = f2bf(a1);
  c[2] = f2bf(a2);
  c[3] = f2bf(a3);
}

extern "C" void kernel_launch(void* const* d_in, const int* in_sizes, int n_in,
                              void* d_out, int out_size, void* d_ws, size_t ws_size,
                              hipStream_t stream) {
  const int* src_seq = (const int*)d_in[0];
  const int* dec_seq = (const int*)d_in[1];
  const float* emb = (const float*)d_in[2];
  const float* Wx_enc = (const float*)d_in[3];
  const float* Wh_enc = (const float*)d_in[4];
  const float* b_enc = (const float*)d_in[5];
  const float* Wx_dec = (const float*)d_in[6];
  const float* Wh_dec = (const float*)d_in[7];
  const float* b_dec = (const float*)d_in[8];
  const float* W_att = (const float*)d_in[9];
  const float* W_out = (const float*)d_in[10];
  const float* b_out = (const float*)d_in[11];

  // Single-phase scratch lives in d_out (262 MB, overwritten by the final GEMM).
  char* ob = (char*)d_out;
  size_t oo = 0;
  auto oalloc = [&](size_t bytes) {
    char* p = ob + oo;
    oo += (bytes + 255) & ~(size_t)255;
    return p;
  };
  unsigned short* WxTe = (unsigned short*)oalloc((size_t)3 * HH * EDIM * 2);
  unsigned short* WhTe = (unsigned short*)oalloc((size_t)3 * HH * HH * 2);
  unsigned short* WxD1T = (unsigned short*)oalloc((size_t)3 * HH * EDIM * 2);
  unsigned short* WxD2T = (unsigned short*)oalloc((size_t)3 * HH * HH * 2);
  unsigned short* WhDT = (unsigned short*)oalloc((size_t)3 * HH * HH * 2);
  unsigned short* WattT = (unsigned short*)oalloc((size_t)HH * HH * 2);
  unsigned short* src_e = (unsigned short*)oalloc((size_t)BATCH * SSRC * EDIM * 2);
  unsigned short* dec_e = (unsigned short*)oalloc((size_t)BATCH * SDEC * EDIM * 2);
  unsigned short* gx_enc = (unsigned short*)oalloc((size_t)BATCH * SSRC * 3 * HH * 2);
  unsigned short* xpart = (unsigned short*)oalloc((size_t)BATCH * SDEC * 3 * HH * 2);
  unsigned short* ench = (unsigned short*)oalloc((size_t)BATCH * SSRC * HH * 2);

  // Buffers alive during the final GEMM live in d_ws (~70 MB).
  char* wb = (char*)d_ws;
  size_t wo = 0;
  auto walloc = [&](size_t bytes) {
    char* p = wb + wo;
    wo += (bytes + 255) & ~(size_t)255;
    return p;
  };
  unsigned short* WoutT = (unsigned short*)walloc((size_t)VOC * HH * 2);
  unsigned short* deco = (unsigned short*)walloc((size_t)BATCH * SDEC * HH * 2);
  float* hf[2];
  unsigned short* hb[2];
  hf[0] = (float*)walloc(BATCH * HH * 4);
  hf[1] = (float*)walloc(BATCH * HH * 4);
  hb[0] = (unsigned short*)walloc(BATCH * HH * 2);
  hb[1] = (unsigned short*)walloc(BATCH * HH * 2);
  unsigned short* svec = (unsigned short*)walloc(BATCH * HH * 2);
  unsigned short* ctxb = (unsigned short*)walloc(BATCH * HH * 2);
  if (wo > ws_size) return;  // insufficient workspace — fail loudly

  dim3 tb(32, 8);
  k_transpose_bf16<<<dim3(3 * HH / 32, EDIM / 32), tb, 0, stream>>>(Wx_enc, WxTe, EDIM, 3 * HH);
  k_transpose_bf16<<<dim3(3 * HH / 32, HH / 32), tb, 0, stream>>>(Wh_enc, WhTe, HH, 3 * HH);
  k_transpose_bf16<<<dim3(3 * HH / 32, EDIM / 32), tb, 0, stream>>>(Wx_dec, WxD1T, EDIM, 3 * HH);
  k_transpose_bf16<<<dim3(3 * HH / 32, HH / 32), tb, 0, stream>>>(Wx_dec + (size_t)EDIM * 3 * HH,
                                                                  WxD2T, HH, 3 * HH);
  k_transpose_bf16<<<dim3(3 * HH / 32, HH / 32), tb, 0, stream>>>(Wh_dec, WhDT, HH, 3 * HH);
  k_transpose_bf16<<<dim3(HH / 32, HH / 32), tb, 0, stream>>>(W_att, WattT, HH, HH);
  k_transpose_bf16<<<dim3(VOC / 32, HH / 32), tb, 0, stream>>>(W_out, WoutT, HH, VOC);

  k_embed<<<BATCH * SSRC, 128, 0, stream>>>(src_seq, emb, src_e);
  k_embed<<<BATCH * SDEC, 128, 0, stream>>>(dec_seq, emb, dec_e);

  k_gemm_bt<1><<<dim3(3 * HH / 128, BATCH * SSRC / 128), 256, 0, stream>>>(
      src_e, WxTe, b_enc, gx_enc, BATCH * SSRC, 3 * HH, EDIM);
  k_gemm_bt<1><<<dim3(3 * HH / 128, BATCH * SDEC / 128), 256, 0, stream>>>(
      dec_e, WxD1T, b_dec, xpart, BATCH * SDEC, 3 * HH, EDIM);

  hipMemsetAsync(hf[0], 0, BATCH * HH * 4, stream);
  hipMemsetAsync(hb[0], 0, BATCH * HH * 2, stream);

  int p = 0;
  for (int t = 0; t < SSRC; t++) {
    k_enc_step<<<64, 192, 0, stream>>>(hb[p], hf[p], gx_enc + (size_t)t * 3 * HH, WhTe, hf[p ^ 1],
                                       hb[p ^ 1], ench + (size_t)t * HH);
    p ^= 1;
  }
  for (int t = 0; t < SDEC; t++) {
    k_gemm_m32<<<HH / 16, 64, 0, stream>>>(hb[p], WattT, svec, HH, HH);
    k_attn<<<BATCH, 256, 0, stream>>>(ench, svec, ctxb);
    k_dec_step<<<64, 384, 0, stream>>>(hb[p], hf[p], ctxb, xpart + (size_t)t * 3 * HH, WxD2T, WhDT,
                                       hf[p ^ 1], hb[p ^ 1], deco + (size_t)t * HH);
    p ^= 1;
  }
  k_gemm_bt<0><<<dim3(VOC / 128, BATCH * SDEC / 128), 256, 0, stream>>>(
      deco, WoutT, b_out, d_out, BATCH * SDEC, VOC, HH);
}

// Round 2
// 7020.908 us; speedup vs baseline: 1.0590x; 1.0590x over previous
//
#include <hip/hip_runtime.h>
#include <hip/hip_bf16.h>

#define HH 1024
#define BATCH 32
#define SSRC 256
#define SDEC 64
#define EDIM 512
#define VOC 32000

typedef __attribute__((ext_vector_type(8))) short bf16x8_t;
typedef __attribute__((ext_vector_type(4))) short s16x4_t;
typedef __attribute__((ext_vector_type(4))) float f32x4_t;

__device__ __forceinline__ float bf2f(unsigned short u) {
  union { float f; unsigned int i; } c; c.i = ((unsigned int)u) << 16; return c.f;
}
__device__ __forceinline__ unsigned short f2bf(float f) {
  union { float f; unsigned int i; } c; c.f = f;
  unsigned int r = c.i + 0x7fffu + ((c.i >> 16) & 1u);
  return (unsigned short)(r >> 16);
}
__device__ __forceinline__ f32x4_t mfma16(bf16x8_t a, bf16x8_t b, f32x4_t c) {
  return __builtin_amdgcn_mfma_f32_16x16x32_bf16(a, b, c, 0, 0, 0);
}

// ---- device-scope generation barrier (all blocks co-resident; 1 block/CU) ----
__device__ __forceinline__ unsigned gridbar(unsigned* cnt, unsigned* gen, unsigned nb, unsigned g) {
  __syncthreads();  // entry barrier: each wave drains its own vmem stores (vmcnt0 before s_barrier)
  if (threadIdx.x == 0) {
    __threadfence();  // agent-scope fence: write-back L2 so other XCDs can see our stores
    unsigned arrived = __hip_atomic_fetch_add(cnt, 1u, __ATOMIC_ACQ_REL, __HIP_MEMORY_SCOPE_AGENT);
    if (arrived == nb - 1u) {
      __hip_atomic_store(cnt, 0u, __ATOMIC_RELAXED, __HIP_MEMORY_SCOPE_AGENT);
      __hip_atomic_store(gen, g + 1u, __ATOMIC_RELEASE, __HIP_MEMORY_SCOPE_AGENT);
    } else {
      while (__hip_atomic_load(gen, __ATOMIC_ACQUIRE, __HIP_MEMORY_SCOPE_AGENT) < g + 1u) {
        __builtin_amdgcn_s_sleep(8);
      }
    }
  }
  __syncthreads();
  return g + 1u;
}

// ---------- transpose f32 (K,N) -> bf16 (N,K) ----------
__global__ void k_transpose_bf16(const float* __restrict__ in, unsigned short* __restrict__ out,
                                 int K, int N) {
  __shared__ float tile[32][33];
  int n0 = blockIdx.x * 32, k0 = blockIdx.y * 32;
  int tx = threadIdx.x, ty = threadIdx.y;
#pragma unroll
  for (int i = 0; i < 4; i++)
    tile[ty + i * 8][tx] = in[(size_t)(k0 + ty + i * 8) * N + (n0 + tx)];
  __syncthreads();
#pragma unroll
  for (int i = 0; i < 4; i++)
    out[(size_t)(n0 + ty + i * 8) * K + (k0 + tx)] = f2bf(tile[tx][ty + i * 8]);
}

// ---------- elementwise cast f32 -> bf16 ----------
__global__ void k_cast_bf16(const float* __restrict__ in, unsigned short* __restrict__ out, int n) {
  int i = (blockIdx.x * blockDim.x + threadIdx.x) * 4;
  if (i < n) {
    float4 v = *(const float4*)(in + i);
    out[i] = f2bf(v.x); out[i + 1] = f2bf(v.y); out[i + 2] = f2bf(v.z); out[i + 3] = f2bf(v.w);
  }
}

// ---------- embedding gather -> bf16 ----------
__global__ void k_embed(const int* __restrict__ seq, const float* __restrict__ emb,
                        unsigned short* __restrict__ out) {
  int t = blockIdx.x;
  int row = seq[t];
  const float* s = emb + (size_t)row * EDIM;
  unsigned short* d = out + (size_t)t * EDIM;
  for (int e = threadIdx.x; e < EDIM; e += blockDim.x) d[e] = f2bf(s[e]);
}

// ---------- big GEMM: C[M,N] = A[M,K](bf16) * B^T[N,K](bf16) + bias ----------
template <int OUT_BF16>
__global__ __launch_bounds__(256) void k_gemm_bt(const unsigned short* __restrict__ A,
                                                 const unsigned short* __restrict__ B,
                                                 const float* __restrict__ bias,
                                                 void* __restrict__ Cv, int M, int N, int K) {
  __shared__ unsigned short As[128 * 32];
  __shared__ unsigned short Bs[128 * 32];
  const int tid = threadIdx.x;
  const int wave = tid >> 6, lane = tid & 63;
  const int row0 = blockIdx.y * 128, col0 = blockIdx.x * 128;
  const int wr = (wave >> 1) * 64, wc = (wave & 1) * 64;
  const int lrow = lane & 15, lk8 = (lane >> 4) * 8;
  f32x4_t acc[4][4] = {};
  const int c1 = wave, c2 = wave + 4;
  const int sr1 = c1 * 16 + (lane >> 2), sr2 = c2 * 16 + (lane >> 2);
  const int sk = (lane & 3) * 8;
  for (int kt = 0; kt < K; kt += 32) {
    __builtin_amdgcn_global_load_lds(
        (const __attribute__((address_space(1))) unsigned int*)(A + (size_t)(row0 + sr1) * K + kt + sk),
        (__attribute__((address_space(3))) unsigned int*)(As + c1 * 512), 16, 0, 0);
    __builtin_amdgcn_global_load_lds(
        (const __attribute__((address_space(1))) unsigned int*)(A + (size_t)(row0 + sr2) * K + kt + sk),
        (__attribute__((address_space(3))) unsigned int*)(As + c2 * 512), 16, 0, 0);
    __builtin_amdgcn_global_load_lds(
        (const __attribute__((address_space(1))) unsigned int*)(B + (size_t)(col0 + sr1) * K + kt + sk),
        (__attribute__((address_space(3))) unsigned int*)(Bs + c1 * 512), 16, 0, 0);
    __builtin_amdgcn_global_load_lds(
        (const __attribute__((address_space(1))) unsigned int*)(B + (size_t)(col0 + sr2) * K + kt + sk),
        (__attribute__((address_space(3))) unsigned int*)(Bs + c2 * 512), 16, 0, 0);
    __syncthreads();
    bf16x8_t af[4], bfr[4];
#pragma unroll
    for (int i = 0; i < 4; i++) {
      af[i] = *(const bf16x8_t*)(As + (wr + i * 16 + lrow) * 32 + lk8);
      bfr[i] = *(const bf16x8_t*)(Bs + (wc + i * 16 + lrow) * 32 + lk8);
    }
#pragma unroll
    for (int i = 0; i < 4; i++)
#pragma unroll
      for (int j = 0; j < 4; j++) acc[i][j] = mfma16(af[i], bfr[j], acc[i][j]);
    __syncthreads();
  }
#pragma unroll
  for (int j = 0; j < 4; j++) {
    int col = col0 + wc + j * 16 + lrow;
    float bv = bias ? bias[col] : 0.0f;
#pragma unroll
    for (int i = 0; i < 4; i++) {
#pragma unroll
      for (int r = 0; r < 4; r++) {
        int row = row0 + wr + i * 16 + (lane >> 4) * 4 + r;
        float v = acc[i][j][r] + bv;
        if (OUT_BF16)
          ((unsigned short*)Cv)[(size_t)row * N + col] = f2bf(v);
        else
          ((float*)Cv)[(size_t)row * N + col] = v;
      }
    }
  }
}

// ---------- persistent encoder scan: 64 blocks x 512 threads, 1 gridbar/step ----------
__global__ __launch_bounds__(512, 2) void k_enc_scan(
    const unsigned short* __restrict__ gx,      // [b][256][3072]
    const unsigned short* __restrict__ WhT,     // [3072][1024]
    unsigned short* __restrict__ ench,          // [b][256][1024]
    float* __restrict__ h0f,                    // [32][1024]
    unsigned* __restrict__ barv) {
  __shared__ __align__(16) unsigned short wlds[3 * 16 * HH];  // 96 KB, XOR-swizzled
  __shared__ float gs[6][32][17];
  __shared__ float hp[32][16];
  __shared__ __align__(16) unsigned short gxl[3][32][16];
  const int tid = threadIdx.x, wave = tid >> 6, lane = tid & 63;
  const int j0 = blockIdx.x * 16;
  const int lrow = lane & 15, lk8 = (lane >> 4) * 8;
  // stage Wh slice (rows g*1024 + j0 + r) into LDS, swizzled
  for (int c = tid; c < 6144; c += 512) {
    int row = c >> 7;
    int ke = (c & 127) * 8;
    bf16x8_t v = *(const bf16x8_t*)(WhT + (size_t)((row >> 4) * HH + j0 + (row & 15)) * HH + ke);
    int byt = ((row * HH + ke) * 2) ^ ((row & 7) << 4);
    *(bf16x8_t*)((char*)wlds + byt) = v;
  }
  hp[tid >> 4][tid & 15] = 0.0f;
  __syncthreads();
  const int b_ = tid >> 4, jj = tid & 15;
  unsigned g = 0;
  for (int t = 0; t < SSRC; ++t) {
    f32x4_t acc0 = {}, acc1 = {};
    if (wave < 6) {
      const int gat = wave >> 1, kh = wave & 1;
      if (t > 0) {
        const unsigned short* hb = ench + (size_t)(t - 1) * HH;
        const int kb = kh * 512;
#pragma unroll 8
        for (int ks = 0; ks < 16; ++ks) {
          int kt = kb + ks * 32;
          int byt = (((gat * 16 + lrow) * HH + kt + lk8) * 2) ^ ((lrow & 7) << 4);
          bf16x8_t bf = *(const bf16x8_t*)((const char*)wlds + byt);
          bf16x8_t x0 = *(const bf16x8_t*)(hb + (size_t)lrow * (SSRC * HH) + kt + lk8);
          bf16x8_t x1 = *(const bf16x8_t*)(hb + (size_t)(lrow + 16) * (SSRC * HH) + kt + lk8);
          acc0 = mfma16(x0, bf, acc0);
          acc1 = mfma16(x1, bf, acc1);
        }
      }
    } else {
      int i = tid - 384;
      if (i < 96) {
        int gat = i >> 5, bb = i & 31;
        const unsigned short* src = gx + (size_t)(bb * SSRC + t) * (3 * HH) + gat * HH + j0;
        *(bf16x8_t*)&gxl[gat][bb][0] = *(const bf16x8_t*)src;
        *(bf16x8_t*)&gxl[gat][bb][8] = *(const bf16x8_t*)(src + 8);
      }
    }
    if (wave < 6) {
#pragma unroll
      for (int r = 0; r < 4; ++r) {
        gs[wave][(lane >> 4) * 4 + r][lrow] = acc0[r];
        gs[wave][(lane >> 4) * 4 + r + 16][lrow] = acc1[r];
      }
    }
    __syncthreads();
    {
      float hz = gs[0][b_][jj] + gs[1][b_][jj];
      float hr = gs[2][b_][jj] + gs[3][b_][jj];
      float hhv = gs[4][b_][jj] + gs[5][b_][jj];
      float xz = bf2f(gxl[0][b_][jj]);
      float xr = bf2f(gxl[1][b_][jj]);
      float xh = bf2f(gxl[2][b_][jj]);
      float z = 1.0f / (1.0f + expf(-(xz + hz)));
      float r = 1.0f / (1.0f + expf(-(xr + hr)));
      float cand = tanhf(xh + r * hhv);
      float hpv = hp[b_][jj];
      float hn = z * hpv + (1.0f - z) * cand;
      hp[b_][jj] = hn;
      ench[(size_t)(b_ * SSRC + t) * HH + j0 + jj] = f2bf(hn);
      if (t == SSRC - 1) h0f[b_ * HH + j0 + jj] = hn;
    }
    g = gridbar(barv, barv + 1, 64, g);
  }
}

// ---------- persistent decoder scan: 96 blocks (64 GEMM + 32 attention), 2 gridbars/step ----------
__global__ __launch_bounds__(512, 2) void k_dec_scan(
    const unsigned short* __restrict__ xpart,   // [b][64][3072]
    const unsigned short* __restrict__ WhDT,    // [3072][1024]
    const unsigned short* __restrict__ WxD2T,   // [3072][1024]
    const unsigned short* __restrict__ ench,    // [b][256][1024]
    const unsigned short* __restrict__ encW,    // [b][256][1024]
    const float* __restrict__ h0f,
    unsigned short* __restrict__ ctxg,          // [32][1024]
    unsigned short* __restrict__ deco,          // [b][64][1024]
    unsigned* __restrict__ barv) {
  __shared__ __align__(16) union SM {
    struct {
      unsigned short wlds[3 * 16 * HH];
      float gs[6][32][17];
      float hp[32][16];
      unsigned short xpl[3][32][16];
    } g;
    struct {
      unsigned short hrow[HH];
      float sc[2][256];
      float red[256];
      float wts[256];
      float ctxp[2][HH];
    } a;
  } sm;
  const int tid = threadIdx.x, wave = tid >> 6, lane = tid & 63;
  const int lrow = lane & 15, lk8 = (lane >> 4) * 8;
  const int blk = blockIdx.x;
  unsigned g = 0;
  if (blk < 64) {
    // ---- GEMM block: owns h columns [j0, j0+16) ----
    const int j0 = blk * 16;
    for (int c = tid; c < 6144; c += 512) {
      int row = c >> 7;
      int ke = (c & 127) * 8;
      bf16x8_t v = *(const bf16x8_t*)(WhDT + (size_t)((row >> 4) * HH + j0 + (row & 15)) * HH + ke);
      int byt = ((row * HH + ke) * 2) ^ ((row & 7) << 4);
      *(bf16x8_t*)((char*)sm.g.wlds + byt) = v;
    }
    const int b_ = tid >> 4, jj = tid & 15;
    sm.g.hp[b_][jj] = h0f[b_ * HH + j0 + jj];
    __syncthreads();
    for (int t = 0; t < SDEC; ++t) {
      const unsigned short* hb = (t == 0) ? (ench + (size_t)(SSRC - 1) * HH)
                                          : (deco + (size_t)(t - 1) * HH);
      const size_t hstr = (t == 0) ? (size_t)(SSRC * HH) : (size_t)(SDEC * HH);
      // P1: gh = h @ WhD (LDS weights) ; waves 6-7 prefetch xpart[t]
      f32x4_t acc0 = {}, acc1 = {};
      if (wave < 6) {
        const int gat = wave >> 1, kh = wave & 1;
        const int kb = kh * 512;
#pragma unroll 8
        for (int ks = 0; ks < 16; ++ks) {
          int kt = kb + ks * 32;
          int byt = (((gat * 16 + lrow) * HH + kt + lk8) * 2) ^ ((lrow & 7) << 4);
          bf16x8_t bf = *(const bf16x8_t*)((const char*)sm.g.wlds + byt);
          bf16x8_t x0 = *(const bf16x8_t*)(hb + (size_t)lrow * hstr + kt + lk8);
          bf16x8_t x1 = *(const bf16x8_t*)(hb + (size_t)(lrow + 16) * hstr + kt + lk8);
          acc0 = mfma16(x0, bf, acc0);
          acc1 = mfma16(x1, bf, acc1);
        }
      } else {
        int i = tid - 384;
        if (i < 96) {
          int gat = i >> 5, bb = i & 31;
          const unsigned short* src = xpart + (size_t)(bb * SDEC + t) * (3 * HH) + gat * HH + j0;
          *(bf16x8_t*)&sm.g.xpl[gat][bb][0] = *(const bf16x8_t*)src;
          *(bf16x8_t*)&sm.g.xpl[gat][bb][8] = *(const bf16x8_t*)(src + 8);
        }
      }
      if (wave < 6) {
#pragma unroll
        for (int r = 0; r < 4; ++r) {
          sm.g.gs[wave][(lane >> 4) * 4 + r][lrow] = acc0[r];
          sm.g.gs[wave][(lane >> 4) * 4 + r + 16][lrow] = acc1[r];
        }
      }
      __syncthreads();
      const float ghz = sm.g.gs[0][b_][jj] + sm.g.gs[1][b_][jj];
      const float ghr = sm.g.gs[2][b_][jj] + sm.g.gs[3][b_][jj];
      const float ghh = sm.g.gs[4][b_][jj] + sm.g.gs[5][b_][jj];
      g = gridbar(barv, barv + 1, 96, g);  // ctx now ready
      // P2: gh_c = ctx @ WxD2 (global weights, L2-hot slice)
      f32x4_t c0 = {}, c1 = {};
      if (wave < 6) {
        const int gat = wave >> 1, kh = wave & 1;
        const int kb = kh * 512;
        const unsigned short* wrow = WxD2T + (size_t)(gat * HH + j0) * HH;
#pragma unroll 8
        for (int ks = 0; ks < 16; ++ks) {
          int kt = kb + ks * 32;
          bf16x8_t bf = *(const bf16x8_t*)(wrow + (size_t)lrow * HH + kt + lk8);
          bf16x8_t x0 = *(const bf16x8_t*)(ctxg + (size_t)lrow * HH + kt + lk8);
          bf16x8_t x1 = *(const bf16x8_t*)(ctxg + (size_t)(lrow + 16) * HH + kt + lk8);
          c0 = mfma16(x0, bf, c0);
          c1 = mfma16(x1, bf, c1);
        }
#pragma unroll
        for (int r = 0; r < 4; ++r) {
          sm.g.gs[wave][(lane >> 4) * 4 + r][lrow] = c0[r];
          sm.g.gs[wave][(lane >> 4) * 4 + r + 16][lrow] = c1[r];
        }
      }
      __syncthreads();
      {
        float cz = sm.g.gs[0][b_][jj] + sm.g.gs[1][b_][jj];
        float cr = sm.g.gs[2][b_][jj] + sm.g.gs[3][b_][jj];
        float ch = sm.g.gs[4][b_][jj] + sm.g.gs[5][b_][jj];
        float xz = bf2f(sm.g.xpl[0][b_][jj]) + cz;
        float xr = bf2f(sm.g.xpl[1][b_][jj]) + cr;
        float xh = bf2f(sm.g.xpl[2][b_][jj]) + ch;
        float z = 1.0f / (1.0f + expf(-(xz + ghz)));
        float r = 1.0f / (1.0f + expf(-(xr + ghr)));
        float cand = tanhf(xh + r * ghh);
        float hpv = sm.g.hp[b_][jj];
        float hn = z * hpv + (1.0f - z) * cand;
        sm.g.hp[b_][jj] = hn;
        deco[(size_t)(b_ * SDEC + t) * HH + j0 + jj] = f2bf(hn);
      }
      g = gridbar(barv, barv + 1, 96, g);
    }
  } else {
    // ---- attention block: one batch ----
    const int b = blk - 64;
    for (int t = 0; t < SDEC; ++t) {
      const unsigned short* hb = (t == 0) ? (ench + (size_t)(b * SSRC + SSRC - 1) * HH)
                                          : (deco + (size_t)(b * SDEC + t - 1) * HH);
      ((unsigned int*)sm.a.hrow)[tid] = ((const unsigned int*)hb)[tid];
      __syncthreads();
      const int s = tid & 255, kh2 = tid >> 8;
      {
        const unsigned short* ew = encW + (size_t)(b * SSRC + s) * HH + kh2 * 512;
        const unsigned short* hr = sm.a.hrow + kh2 * 512;
        float p0 = 0, p1 = 0, p2 = 0, p3 = 0;
#pragma unroll 8
        for (int i = 0; i < 64; ++i) {
          bf16x8_t e = *(const bf16x8_t*)(ew + i * 8);
          bf16x8_t hv = *(const bf16x8_t*)(hr + i * 8);
          p0 += bf2f((unsigned short)e[0]) * bf2f((unsigned short)hv[0]);
          p1 += bf2f((unsigned short)e[1]) * bf2f((unsigned short)hv[1]);
          p2 += bf2f((unsigned short)e[2]) * bf2f((unsigned short)hv[2]);
          p3 += bf2f((unsigned short)e[3]) * bf2f((unsigned short)hv[3]);
          p0 += bf2f((unsigned short)e[4]) * bf2f((unsigned short)hv[4]);
          p1 += bf2f((unsigned short)e[5]) * bf2f((unsigned short)hv[5]);
          p2 += bf2f((unsigned short)e[6]) * bf2f((unsigned short)hv[6]);
          p3 += bf2f((unsigned short)e[7]) * bf2f((unsigned short)hv[7]);
        }
        sm.a.sc[kh2][s] = (p0 + p1) + (p2 + p3);
      }
      __syncthreads();
      float score = 0.0f, e = 0.0f;
      if (tid < 256) { score = sm.a.sc[0][tid] + sm.a.sc[1][tid]; sm.a.red[tid] = score; }
      __syncthreads();
      for (int o = 128; o > 0; o >>= 1) {
        if (tid < o) sm.a.red[tid] = fmaxf(sm.a.red[tid], sm.a.red[tid + o]);
        __syncthreads();
      }
      float mx = sm.a.red[0];
      __syncthreads();
      if (tid < 256) { e = expf(score - mx); sm.a.red[tid] = e; }
      __syncthreads();
      for (int o = 128; o > 0; o >>= 1) {
        if (tid < o) sm.a.red[tid] += sm.a.red[tid + o];
        __syncthreads();
      }
      float inv = 1.0f / sm.a.red[0];
      __syncthreads();
      if (tid < 256) sm.a.wts[tid] = e * inv;
      __syncthreads();
      {
        const int c4 = (tid & 255) * 4;
        const int sh = kh2 * 128;
        float a0 = 0, a1 = 0, a2 = 0, a3 = 0;
#pragma unroll 4
        for (int si = 0; si < 128; ++si) {
          float w = sm.a.wts[sh + si];
          s16x4_t v = *(const s16x4_t*)(ench + (size_t)(b * SSRC + sh + si) * HH + c4);
          a0 += w * bf2f((unsigned short)v[0]);
          a1 += w * bf2f((unsigned short)v[1]);
          a2 += w * bf2f((unsigned short)v[2]);
          a3 += w * bf2f((unsigned short)v[3]);
        }
        sm.a.ctxp[kh2][c4 + 0] = a0;
        sm.a.ctxp[kh2][c4 + 1] = a1;
        sm.a.ctxp[kh2][c4 + 2] = a2;
        sm.a.ctxp[kh2][c4 + 3] = a3;
      }
      __syncthreads();
      {
        int c2 = tid * 2;
        float v0 = sm.a.ctxp[0][c2] + sm.a.ctxp[1][c2];
        float v1 = sm.a.ctxp[0][c2 + 1] + sm.a.ctxp[1][c2 + 1];
        unsigned int pk = (unsigned int)f2bf(v0) | ((unsigned int)f2bf(v1) << 16);
        ((unsigned int*)ctxg)[b * (HH / 2) + tid] = pk;
      }
      g = gridbar(barv, barv + 1, 96, g);  // publish ctx
      g = gridbar(barv, barv + 1, 96, g);  // idle through P2
    }
  }
}

extern "C" void kernel_launch(void* const* d_in, const int* in_sizes, int n_in,
                              void* d_out, int out_size, void* d_ws, size_t ws_size,
                              hipStream_t stream) {
  const int* src_seq = (const int*)d_in[0];
  const int* dec_seq = (const int*)d_in[1];
  const float* emb = (const float*)d_in[2];
  const float* Wx_enc = (const float*)d_in[3];
  const float* Wh_enc = (const float*)d_in[4];
  const float* b_enc = (const float*)d_in[5];
  const float* Wx_dec = (const float*)d_in[6];
  const float* Wh_dec = (const float*)d_in[7];
  const float* b_dec = (const float*)d_in[8];
  const float* W_att = (const float*)d_in[9];
  const float* W_out = (const float*)d_in[10];
  const float* b_out = (const float*)d_in[11];

  // Single-phase scratch in d_out (~134 MB < 262 MB; overwritten by final GEMM).
  char* ob = (char*)d_out;
  size_t oo = 0;
  auto oalloc = [&](size_t bytes) {
    char* p = ob + oo;
    oo += (bytes + 255) & ~(size_t)255;
    return p;
  };
  unsigned short* WxTe = (unsigned short*)oalloc((size_t)3 * HH * EDIM * 2);
  unsigned short* WhTe = (unsigned short*)oalloc((size_t)3 * HH * HH * 2);
  unsigned short* WxD1T = (unsigned short*)oalloc((size_t)3 * HH * EDIM * 2);
  unsigned short* WxD2T = (unsigned short*)oalloc((size_t)3 * HH * HH * 2);
  unsigned short* WhDT = (unsigned short*)oalloc((size_t)3 * HH * HH * 2);
  unsigned short* Wattb = (unsigned short*)oalloc((size_t)HH * HH * 2);
  unsigned short* src_e = (unsigned short*)oalloc((size_t)BATCH * SSRC * EDIM * 2);
  unsigned short* dec_e = (unsigned short*)oalloc((size_t)BATCH * SDEC * EDIM * 2);
  unsigned short* gx_enc = (unsigned short*)oalloc((size_t)BATCH * SSRC * 3 * HH * 2);
  unsigned short* xpart = (unsigned short*)oalloc((size_t)BATCH * SDEC * 3 * HH * 2);
  unsigned short* ench = (unsigned short*)oalloc((size_t)BATCH * SSRC * HH * 2);
  unsigned short* encW = (unsigned short*)oalloc((size_t)BATCH * SSRC * HH * 2);

  // Alive during final GEMM -> d_ws (~70 MB).
  char* wb = (char*)d_ws;
  size_t wo = 0;
  auto walloc = [&](size_t bytes) {
    char* p = wb + wo;
    wo += (bytes + 255) & ~(size_t)255;
    return p;
  };
  unsigned short* WoutT = (unsigned short*)walloc((size_t)VOC * HH * 2);
  unsigned short* deco = (unsigned short*)walloc((size_t)BATCH * SDEC * HH * 2);
  float* h0f = (float*)walloc(BATCH * HH * 4);
  unsigned short* ctxb = (unsigned short*)walloc(BATCH * HH * 2);
  unsigned* bars = (unsigned*)walloc(256);
  if (wo > ws_size) return;

  dim3 tb(32, 8);
  k_transpose_bf16<<<dim3(3 * HH / 32, EDIM / 32), tb, 0, stream>>>(Wx_enc, WxTe, EDIM, 3 * HH);
  k_transpose_bf16<<<dim3(3 * HH / 32, HH / 32), tb, 0, stream>>>(Wh_enc, WhTe, HH, 3 * HH);
  k_transpose_bf16<<<dim3(3 * HH / 32, EDIM / 32), tb, 0, stream>>>(Wx_dec, WxD1T, EDIM, 3 * HH);
  k_transpose_bf16<<<dim3(3 * HH / 32, HH / 32), tb, 0, stream>>>(Wx_dec + (size_t)EDIM * 3 * HH,
                                                                  WxD2T, HH, 3 * HH);
  k_transpose_bf16<<<dim3(3 * HH / 32, HH / 32), tb, 0, stream>>>(Wh_dec, WhDT, HH, 3 * HH);
  k_transpose_bf16<<<dim3(VOC / 32, HH / 32), tb, 0, stream>>>(W_out, WoutT, HH, VOC);
  k_cast_bf16<<<(HH * HH / 4) / 256, 256, 0, stream>>>(W_att, Wattb, HH * HH);

  k_embed<<<BATCH * SSRC, 128, 0, stream>>>(src_seq, emb, src_e);
  k_embed<<<BATCH * SDEC, 128, 0, stream>>>(dec_seq, emb, dec_e);

  k_gemm_bt<1><<<dim3(3 * HH / 128, BATCH * SSRC / 128), 256, 0, stream>>>(
      src_e, WxTe, b_enc, gx_enc, BATCH * SSRC, 3 * HH, EDIM);
  k_gemm_bt<1><<<dim3(3 * HH / 128, BATCH * SDEC / 128), 256, 0, stream>>>(
      dec_e, WxD1T, b_dec, xpart, BATCH * SDEC, 3 * HH, EDIM);

  hipMemsetAsync(bars, 0, 256, stream);

  k_enc_scan<<<64, 512, 0, stream>>>(gx_enc, WhTe, ench, h0f, bars);

  // encW = ench @ W_att^T  (scores reassociation)
  k_gemm_bt<1><<<dim3(HH / 128, BATCH * SSRC / 128), 256, 0, stream>>>(
      ench, Wattb, nullptr, encW, BATCH * SSRC, HH, HH);

  k_dec_scan<<<96, 512, 0, stream>>>(xpart, WhDT, WxD2T, ench, encW, h0f, ctxb, deco, bars + 8);

  k_gemm_bt<0><<<dim3(VOC / 128, BATCH * SDEC / 128), 256, 0, stream>>>(
      deco, WoutT, b_out, d_out, BATCH * SDEC, VOC, HH);
}